// Round 14
// baseline (372.597 us; speedup 1.0000x reference)
//
#include <hip/hip_runtime.h>
#include <hip/hip_bf16.h>

#define HC 256

typedef __attribute__((ext_vector_type(8))) short bf16x8;
typedef __attribute__((ext_vector_type(4))) float f32x4;
typedef __attribute__((ext_vector_type(2))) float f32x2;

__device__ __forceinline__ void gl_lds16(const void* g, void* l) {
  __builtin_amdgcn_global_load_lds(
      (const __attribute__((address_space(1))) unsigned int*)g,
      (__attribute__((address_space(3))) unsigned int*)l, 16, 0, 0);
}

// ==== bf16 weight casts (both layers) + dst-degree histogram, one kernel ===
__device__ __forceinline__ void cast_w_one(const float* Wl, const float* Wr,
                                           ushort* WT, int F, int idx) {
  int col = idx / F, f = idx - col * F;
  float v = (col < 256) ? Wl[col * F + f] : Wr[(col - 256) * F + f];
  __hip_bfloat16 h = __float2bfloat16(v);
  WT[(size_t)col * F + f] = *(ushort*)&h;
}

__global__ void k_weights_hist(const float* __restrict__ Wl1, const float* __restrict__ Wr1,
                               ushort* __restrict__ WT1, const float* __restrict__ Wl2,
                               const float* __restrict__ Wr2, ushort* __restrict__ WT2,
                               const int* __restrict__ ei, int* __restrict__ deg, int E_) {
  int idx = blockIdx.x * blockDim.x + threadIdx.x;
  const int t1 = 512 * 128, t2 = 512 * 64;
  if (idx < t1) {
    cast_w_one(Wl1, Wr1, WT1, 128, idx);
  } else if (idx < t1 + t2) {
    cast_w_one(Wl2, Wr2, WT2, 64, idx - t1);
  } else {
    int e = idx - t1 - t2;
    if (e < E_) atomicAdd(&deg[ei[E_ + e]], 1);
  }
}

// ======== MFMA GEMM: K-pipelined, disjoint LDS buffers per K-step ==========
// 4 waves, 128x128 block tile, 64x64 wave tile, BK=64.
// Flow (NSTEP=2): load(0); bar; load(1); mfma(0); bar; mfma(1) — step-1 DMAs
// overlap step-0 MFMAs; one barrier-drain removed vs looped version.
// Epilogue stages C in LDS (alias, pitch 136) -> coalesced 16B stores.
template <int F>
__global__ __launch_bounds__(256) void gemm_mfma(const ushort* __restrict__ A,
                                                 const ushort* __restrict__ WT,
                                                 ushort* __restrict__ xlb,
                                                 ushort* __restrict__ xrb, int n_nodes) {
  constexpr int NSTEP = F / 64;
  constexpr int SM = (2 * NSTEP * 8192 > 17408) ? 2 * NSTEP * 8192 : 17408;
  __shared__ __align__(16) ushort smem[SM];
  const int tid = threadIdx.x;
  const int wv = tid >> 6, lane = tid & 63;
  const int m16 = lane & 15, quad = lane >> 4;
  const int col0 = blockIdx.x * 128;  // 0,1 -> xl ; 2,3 -> xr
  const int row0 = blockIdx.y * 128;
  const int wm = (wv >> 1) * 64, wn = (wv & 1) * 64;

  f32x4 acc[4][4];
#pragma unroll
  for (int i = 0; i < 4; ++i)
#pragma unroll
    for (int j = 0; j < 4; ++j) acc[i][j] = (f32x4){0.f, 0.f, 0.f, 0.f};

  auto load_step = [&](int s) {
    ushort* As = smem + s * 16384;
    ushort* Bs = As + 8192;
    const int khat = s * 64;
#pragma unroll
    for (int t = 0; t < 4; ++t) {
      const int sl16 = tid + 256 * t;  // LDS slot (16B units), linear in lane
      const int row = sl16 >> 3, sl = sl16 & 7;
      const int gch = sl ^ (row & 7);  // swizzle on the GLOBAL address
      const int grow = row0 + row;
      if (grow < n_nodes)
        gl_lds16(A + (size_t)grow * F + khat + gch * 8, As + sl16 * 8);
      gl_lds16(WT + (size_t)(col0 + row) * F + khat + gch * 8, Bs + sl16 * 8);
    }
  };

  auto mfma_step = [&](int s) {
    ushort* As = smem + s * 16384;
    ushort* Bs = As + 8192;
#pragma unroll
    for (int kh = 0; kh < 2; ++kh) {
      bf16x8 af[4], bf[4];
#pragma unroll
      for (int i = 0; i < 4; ++i) {
        const int row = wm + i * 16 + m16;
        const int slot = (kh * 4 + quad) ^ (row & 7);
        af[i] = *(bf16x8*)&As[row * 64 + slot * 8];
      }
#pragma unroll
      for (int j = 0; j < 4; ++j) {
        const int col = wn + j * 16 + m16;
        const int slot = (kh * 4 + quad) ^ (col & 7);
        bf[j] = *(bf16x8*)&Bs[col * 64 + slot * 8];
      }
#pragma unroll
      for (int i = 0; i < 4; ++i)
#pragma unroll
        for (int j = 0; j < 4; ++j)
          acc[i][j] =
              __builtin_amdgcn_mfma_f32_16x16x32_bf16(af[i], bf[j], acc[i][j], 0, 0, 0);
    }
  };

  load_step(0);
  __syncthreads();
  if (NSTEP > 1) load_step(1);  // DMAs overlap mfma_step(0)
  mfma_step(0);
  if (NSTEP > 1) {
    __syncthreads();  // drains step-1 loads (had mfma(0) time to land)
    mfma_step(1);
  }

  // ---- epilogue: acc -> bf16 -> LDS (pitch 136) -> coalesced 16B stores ----
  __syncthreads();  // all LDS reads done; safe to alias with Ct
  ushort* Ct = smem;
#pragma unroll
  for (int i = 0; i < 4; ++i) {
#pragma unroll
    for (int r = 0; r < 4; ++r) {
      const int row = wm + i * 16 + quad * 4 + r;
#pragma unroll
      for (int j = 0; j < 4; ++j) {
        __hip_bfloat16 h = __float2bfloat16(acc[i][j][r]);
        Ct[row * 136 + wn + j * 16 + m16] = *(ushort*)&h;
      }
    }
  }
  __syncthreads();
  const bool is_xl = (col0 < 256);
  ushort* dst = is_xl ? xlb : xrb;
  const int cb = is_xl ? col0 : (col0 - 256);
  const int chunk = tid & 15;  // 16B chunk within the 256B row
#pragma unroll
  for (int it = 0; it < 8; ++it) {
    const int row = (tid >> 4) + 16 * it;
    const int grow = row0 + row;
    int4 v = *(int4*)&Ct[row * 136 + chunk * 8];
    if (grow < n_nodes)
      *(int4*)(dst + (size_t)grow * 256 + cb + chunk * 8) = v;
  }
}

// ============ CSR scan: ONE kernel, one 1024-thread block ==================
// Thread t serially sums deg over its contiguous range, block-scans the 1024
// sums (Hillis-Steele in LDS), then serially writes rowstart/cursor.
__global__ __launch_bounds__(1024) void k_scan_all(const int* __restrict__ deg,
                                                   int* __restrict__ rowstart,
                                                   int* __restrict__ cursor,
                                                   float4* __restrict__ sea,
                                                   int n, int E_) {
  __shared__ int a[1024], b[1024];
  const int t = threadIdx.x;
  const int per = (n + 1023) / 1024;
  const int lo = t * per, hi = min(n, lo + per);
  int s = 0;
  for (int i = lo; i < hi; ++i) s += deg[i];
  a[t] = s;
  __syncthreads();
  int* cur = a;
  int* nxt = b;
  for (int off = 1; off < 1024; off <<= 1) {
    int x = cur[t];
    if (t >= off) x += cur[t - off];
    nxt[t] = x;
    __syncthreads();
    int* tmp = cur; cur = nxt; nxt = tmp;
  }
  int run = cur[t] - s;  // exclusive prefix
  for (int i = lo; i < hi; ++i) {
    rowstart[i] = run;
    cursor[i] = run;
    run += deg[i];
  }
  if (t == 0) rowstart[n] = E_;
  if (t < 8) sea[E_ + t] = make_float4(0.f, 0.f, 0.f, 0.f);
}

// ==== fused: cast x -> bf16 A AND CSR edge scatter (src packed in sea.w) ===
__global__ void k_prep(const float* __restrict__ x, ushort* __restrict__ A,
                       const int* __restrict__ ei, const float* __restrict__ ea,
                       int* __restrict__ cursor, float4* __restrict__ sea,
                       int n, int E_) {
  const int nx8 = n * 16;  // 8 elements per thread
  int idx = blockIdx.x * blockDim.x + threadIdx.x;
  if (idx < nx8) {
    const float4* xp = (const float4*)x + (size_t)idx * 2;
    float4 v0 = xp[0], v1 = xp[1];
    float vv[8] = {v0.x, v0.y, v0.z, v0.w, v1.x, v1.y, v1.z, v1.w};
    __align__(16) ushort hb[8];
#pragma unroll
    for (int j = 0; j < 8; ++j) {
      __hip_bfloat16 h = __float2bfloat16(vv[j]);
      hb[j] = *(ushort*)&h;
    }
    *(int4*)(A + (size_t)idx * 8) = *(int4*)hb;
  } else {
    int e = idx - nx8;
    if (e < E_) {
      int dst = ei[E_ + e];
      int pos = atomicAdd(&cursor[dst], 1);
      sea[pos] = make_float4(ea[e * 3], ea[e * 3 + 1], ea[e * 3 + 2],
                             __int_as_float(ei[e]));
    }
  }
}

// ================= fused per-destination attention =========================
// ONE wave per workgroup; chunk dsts per wave; 4-edge software pipeline; src
// index packed in sea.w. MODE 0: bf16 h out. MODE 1: fp32 + PReLU.
__device__ __forceinline__ f32x2 vmax2(f32x2 a, f32x2 b) {
  return (f32x2){fmaxf(a.x, b.x), fmaxf(a.y, b.y)};
}
__device__ __forceinline__ f32x2 vmin2(f32x2 a, f32x2 b) {
  return (f32x2){fminf(a.x, b.x), fminf(a.y, b.y)};
}

__device__ __forceinline__ void edge_step(
    const ushort4& lu, const float4& eav, const f32x2* we0, const f32x2* we1,
    const f32x2* we2, const f32x2* at, const f32x2* xrl, f32x2& num01,
    f32x2& num23, float& den) {
  f32x2 lav0, lav1;
  lav0.x = __uint_as_float((unsigned)lu.x << 16);
  lav0.y = __uint_as_float((unsigned)lu.y << 16);
  lav1.x = __uint_as_float((unsigned)lu.z << 16);
  lav1.y = __uint_as_float((unsigned)lu.w << 16);
  const f32x2 zero = {0.f, 0.f};
  const f32x2 slope = {0.2f, 0.2f};
  f32x2 pv = zero;
#pragma unroll
  for (int j = 0; j < 2; ++j) {
    f32x2 la = (j == 0) ? lav0 : lav1;
    f32x2 ev = we0[j] * eav.x + we1[j] * eav.y + we2[j] * eav.z;
    f32x2 s = la + xrl[j] + ev;
    f32x2 z = vmax2(s, zero) + slope * vmin2(s, zero);
    pv = pv + z * at[j];
  }
  float p = pv.x + pv.y;
  p += __shfl_xor(p, 1);
  p += __shfl_xor(p, 2);
  p += __shfl_xor(p, 4);
  p += __shfl_xor(p, 8);
  const float w = __expf(p);  // |logit| << 80: no max-subtraction needed
  den += w;
  num01 = num01 + (f32x2){w, w} * lav0;
  num23 = num23 + (f32x2){w, w} * lav1;
}

template <int MODE>
__global__ __launch_bounds__(64) void fused_attn(
    const ushort* __restrict__ xlb, const ushort* __restrict__ xrb,
    const int* __restrict__ rowstart, const float4* __restrict__ sea,
    const float* __restrict__ We, const float* __restrict__ att,
    const float* __restrict__ bias, const float* __restrict__ pw,
    float* __restrict__ out, ushort* __restrict__ outs, int n, int chunk) {
  const int lane = threadIdx.x;
  const int d0 = blockIdx.x * chunk;
  if (d0 >= n) return;
  const int d1 = min(d0 + chunk, n);

  // ---- prologue (amortized over the chunk) ----
  f32x2 we0[2], we1[2], we2[2], at[2];
#pragma unroll
  for (int j = 0; j < 4; ++j) {
    int r = 4 * lane + j;
    ((float*)we0)[j] = We[r * 3 + 0];
    ((float*)we1)[j] = We[r * 3 + 1];
    ((float*)we2)[j] = We[r * 3 + 2];
    ((float*)at)[j] = att[r];
  }
  const float4 bias4 = ((const float4*)bias)[lane & 15];
  float4 pw4 = {0.f, 0.f, 0.f, 0.f};
  if (MODE == 1) pw4 = ((const float4*)pw)[lane & 15];
  const ushort4* xlb4 = (const ushort4*)xlb;

  for (int d = d0; d < d1; ++d) {
    const ushort4 xu = ((const ushort4*)xrb)[(unsigned)(d * 64) + lane];
    f32x2 xrl[2];
    xrl[0].x = __uint_as_float((unsigned)xu.x << 16);
    xrl[0].y = __uint_as_float((unsigned)xu.y << 16);
    xrl[1].x = __uint_as_float((unsigned)xu.z << 16);
    xrl[1].y = __uint_as_float((unsigned)xu.w << 16);

    int pos = rowstart[d];
    const int end = rowstart[d + 1];
    f32x2 num01 = {0.f, 0.f}, num23 = {0.f, 0.f};
    float den = 0.f;

    if (pos < end) {
      // CSR padded by 8 zero entries past E: over-read safe; pad/next-dst
      // entries are fetched but never processed. src index rides in sea.w.
      float4 e0 = sea[pos], e1 = sea[pos + 1], e2 = sea[pos + 2], e3 = sea[pos + 3];
      ushort4 g0 = xlb4[(unsigned)(__float_as_int(e0.w) * 64) + lane];
      ushort4 g1 = xlb4[(unsigned)(__float_as_int(e1.w) * 64) + lane];
      ushort4 g2 = xlb4[(unsigned)(__float_as_int(e2.w) * 64) + lane];
      ushort4 g3 = xlb4[(unsigned)(__float_as_int(e3.w) * 64) + lane];

      while (pos + 4 <= end) {
        ushort4 h0 = g0, h1 = g1, h2 = g2, h3 = g3;
        float4 f0 = e0, f1 = e1, f2 = e2, f3 = e3;
        if (pos + 4 < end) {  // uniform branch: prefetch only if more edges
          f0 = sea[pos + 4];
          f1 = sea[pos + 5];
          f2 = sea[pos + 6];
          f3 = sea[pos + 7];
          h0 = xlb4[(unsigned)(__float_as_int(f0.w) * 64) + lane];
          h1 = xlb4[(unsigned)(__float_as_int(f1.w) * 64) + lane];
          h2 = xlb4[(unsigned)(__float_as_int(f2.w) * 64) + lane];
          h3 = xlb4[(unsigned)(__float_as_int(f3.w) * 64) + lane];
        }
        edge_step(g0, e0, we0, we1, we2, at, xrl, num01, num23, den);
        edge_step(g1, e1, we0, we1, we2, at, xrl, num01, num23, den);
        edge_step(g2, e2, we0, we1, we2, at, xrl, num01, num23, den);
        edge_step(g3, e3, we0, we1, we2, at, xrl, num01, num23, den);
        g0 = h0; g1 = h1; g2 = h2; g3 = h3;
        e0 = f0; e1 = f1; e2 = f2; e3 = f3;
        pos += 4;
      }
      const int rem = end - pos;  // 0..3, wave-uniform
      if (rem > 0) edge_step(g0, e0, we0, we1, we2, at, xrl, num01, num23, den);
      if (rem > 1) edge_step(g1, e1, we0, we1, we2, at, xrl, num01, num23, den);
      if (rem > 2) edge_step(g2, e2, we0, we1, we2, at, xrl, num01, num23, den);
    }

    const float inv = 1.f / (den + 1e-16f);
    float4 r;
    r.x = num01.x * inv;
    r.y = num01.y * inv;
    r.z = num23.x * inv;
    r.w = num23.y * inv;
    // combine 4 heads: lanes {m, m+16, m+32, m+48} hold the same channels
    r.x += __shfl_xor(r.x, 16);
    r.y += __shfl_xor(r.y, 16);
    r.z += __shfl_xor(r.z, 16);
    r.w += __shfl_xor(r.w, 16);
    r.x += __shfl_xor(r.x, 32);
    r.y += __shfl_xor(r.y, 32);
    r.z += __shfl_xor(r.z, 32);
    r.w += __shfl_xor(r.w, 32);
    if (lane < 16) {
      float o[4];
      o[0] = 0.25f * r.x + bias4.x;
      o[1] = 0.25f * r.y + bias4.y;
      o[2] = 0.25f * r.z + bias4.z;
      o[3] = 0.25f * r.w + bias4.w;
      if (MODE == 1) {
        const float pwv[4] = {pw4.x, pw4.y, pw4.z, pw4.w};
#pragma unroll
        for (int j = 0; j < 4; ++j) o[j] = (o[j] >= 0.f) ? o[j] : pwv[j] * o[j];
        ((float4*)out)[(size_t)d * 16 + lane] = make_float4(o[0], o[1], o[2], o[3]);
      } else {
        ushort hb[4];
#pragma unroll
        for (int j = 0; j < 4; ++j) {
          __hip_bfloat16 h = __float2bfloat16(o[j]);
          hb[j] = *(ushort*)&h;
        }
        *(ushort4*)(outs + (size_t)d * 64 + 4 * lane) =
            make_ushort4(hb[0], hb[1], hb[2], hb[3]);
      }
    }
  }
}

extern "C" void kernel_launch(void* const* d_in, const int* in_sizes, int n_in,
                              void* d_out, int out_size, void* d_ws, size_t ws_size,
                              hipStream_t stream) {
  const float* x    = (const float*)d_in[0];
  const int*   ei   = (const int*)d_in[1];
  const float* ea   = (const float*)d_in[2];
  const float* Wl1  = (const float*)d_in[3];
  const float* Wr1  = (const float*)d_in[4];
  const float* We1  = (const float*)d_in[5];
  const float* att1 = (const float*)d_in[6];
  const float* b1   = (const float*)d_in[7];
  const float* Wl2  = (const float*)d_in[8];
  const float* Wr2  = (const float*)d_in[9];
  const float* We2  = (const float*)d_in[10];
  const float* att2 = (const float*)d_in[11];
  const float* b2   = (const float*)d_in[12];
  const float* pw   = (const float*)d_in[13];
  const int N_ = in_sizes[0] / 128;
  const int E_ = in_sizes[1] / 2;
  float* out = (float*)d_out;

  char* w = (char*)d_ws;
  auto alloc = [&](size_t bytes) {
    char* p = w;
    w += (bytes + 255) & ~size_t(255);
    return p;
  };
  ushort* xlb      = (ushort*)alloc((size_t)N_ * 256 * 2);   // bf16 gather operand
  ushort* xrb      = (ushort*)alloc((size_t)N_ * 256 * 2);   // bf16 logit operand
  ushort* Ax       = (ushort*)alloc((size_t)N_ * 128 * 2);   // bf16 cast of x
  ushort* h2       = (ushort*)alloc((size_t)N_ * 64 * 2);    // bf16 h (layer-2 A)
  float4* sea      = (float4*)alloc((size_t)(E_ + 8) * 16);  // {ea0,ea1,ea2,src}
  int*    deg      = (int*)alloc((size_t)N_ * 4);
  int*    rowstart = (int*)alloc((size_t)(N_ + 1) * 4);
  int*    cursor   = (int*)alloc((size_t)N_ * 4);
  ushort* WT1      = (ushort*)alloc((size_t)512 * 128 * 2);
  ushort* WT2      = (ushort*)alloc((size_t)512 * 64 * 2);

  // ---- weight casts + histogram (deg zeroed via async memset) ----
  hipMemsetAsync(deg, 0, (size_t)N_ * 4, stream);
  const int wtot = 512 * 128 + 512 * 64 + E_;
  k_weights_hist<<<(wtot + 255) / 256, 256, 0, stream>>>(Wl1, Wr1, WT1, Wl2, Wr2, WT2,
                                                         ei, deg, E_);

  // ---- CSR scan (single kernel) + x cast + edge scatter ----
  k_scan_all<<<1, 1024, 0, stream>>>(deg, rowstart, cursor, sea, N_, E_);
  const int ptot = N_ * 16 + E_;
  k_prep<<<(ptot + 255) / 256, 256, 0, stream>>>(x, Ax, ei, ea, cursor, sea, N_, E_);

  const dim3 GG(4, (N_ + 127) / 128);  // x: col-blocks (xl,xl,xr,xr); y: rows
  const int chunk = 2;                 // dsts per wave
  const int FB = (N_ + chunk - 1) / chunk;  // one wave per block

  // ---- layer 1 ----
  gemm_mfma<128><<<GG, 256, 0, stream>>>(Ax, WT1, xlb, xrb, N_);
  fused_attn<0><<<FB, 64, 0, stream>>>(xlb, xrb, rowstart, sea, We1, att1,
                                       b1, pw, nullptr, h2, N_, chunk);
  // ---- layer 2 ----
  gemm_mfma<64><<<GG, 256, 0, stream>>>(h2, WT2, xlb, xrb, N_);
  fused_attn<1><<<FB, 64, 0, stream>>>(xlb, xrb, rowstart, sea, We2, att2,
                                       b2, pw, out, nullptr, N_, chunk);
}

// Round 15
// 266.623 us; speedup vs baseline: 1.3975x; 1.3975x over previous
//
#include <hip/hip_runtime.h>
#include <hip/hip_bf16.h>

#define HC 256

typedef __attribute__((ext_vector_type(8))) short bf16x8;
typedef __attribute__((ext_vector_type(4))) float f32x4;
typedef __attribute__((ext_vector_type(2))) float f32x2;

__device__ __forceinline__ void gl_lds16(const void* g, void* l) {
  __builtin_amdgcn_global_load_lds(
      (const __attribute__((address_space(1))) unsigned int*)g,
      (__attribute__((address_space(3))) unsigned int*)l, 16, 0, 0);
}

// ==== bf16 weight casts (both layers) + dst-degree histogram, one kernel ===
__device__ __forceinline__ void cast_w_one(const float* Wl, const float* Wr,
                                           ushort* WT, int F, int idx) {
  int col = idx / F, f = idx - col * F;
  float v = (col < 256) ? Wl[col * F + f] : Wr[(col - 256) * F + f];
  __hip_bfloat16 h = __float2bfloat16(v);
  WT[(size_t)col * F + f] = *(ushort*)&h;
}

__global__ void k_weights_hist(const float* __restrict__ Wl1, const float* __restrict__ Wr1,
                               ushort* __restrict__ WT1, const float* __restrict__ Wl2,
                               const float* __restrict__ Wr2, ushort* __restrict__ WT2,
                               const int* __restrict__ ei, int* __restrict__ deg, int E_) {
  int idx = blockIdx.x * blockDim.x + threadIdx.x;
  const int t1 = 512 * 128, t2 = 512 * 64;
  if (idx < t1) {
    cast_w_one(Wl1, Wr1, WT1, 128, idx);
  } else if (idx < t1 + t2) {
    cast_w_one(Wl2, Wr2, WT2, 64, idx - t1);
  } else {
    int e = idx - t1 - t2;
    if (e < E_) atomicAdd(&deg[ei[E_ + e]], 1);
  }
}

// ======== MFMA GEMM: K-pipelined, disjoint LDS buffers per K-step ==========
// 4 waves, 128x128 block tile, 64x64 wave tile, BK=64.
// Flow (NSTEP=2): load(0); bar; load(1); mfma(0); bar; mfma(1) — step-1 DMAs
// overlap step-0 MFMAs. Epilogue: C via LDS (pitch 136) -> coalesced stores.
template <int F>
__global__ __launch_bounds__(256) void gemm_mfma(const ushort* __restrict__ A,
                                                 const ushort* __restrict__ WT,
                                                 ushort* __restrict__ xlb,
                                                 ushort* __restrict__ xrb, int n_nodes) {
  constexpr int NSTEP = F / 64;
  constexpr int SM = (2 * NSTEP * 8192 > 17408) ? 2 * NSTEP * 8192 : 17408;
  __shared__ __align__(16) ushort smem[SM];
  const int tid = threadIdx.x;
  const int wv = tid >> 6, lane = tid & 63;
  const int m16 = lane & 15, quad = lane >> 4;
  const int col0 = blockIdx.x * 128;  // 0,1 -> xl ; 2,3 -> xr
  const int row0 = blockIdx.y * 128;
  const int wm = (wv >> 1) * 64, wn = (wv & 1) * 64;

  f32x4 acc[4][4];
#pragma unroll
  for (int i = 0; i < 4; ++i)
#pragma unroll
    for (int j = 0; j < 4; ++j) acc[i][j] = (f32x4){0.f, 0.f, 0.f, 0.f};

  auto load_step = [&](int s) {
    ushort* As = smem + s * 16384;
    ushort* Bs = As + 8192;
    const int khat = s * 64;
#pragma unroll
    for (int t = 0; t < 4; ++t) {
      const int sl16 = tid + 256 * t;  // LDS slot (16B units), linear in lane
      const int row = sl16 >> 3, sl = sl16 & 7;
      const int gch = sl ^ (row & 7);  // swizzle on the GLOBAL address
      const int grow = row0 + row;
      if (grow < n_nodes)
        gl_lds16(A + (size_t)grow * F + khat + gch * 8, As + sl16 * 8);
      gl_lds16(WT + (size_t)(col0 + row) * F + khat + gch * 8, Bs + sl16 * 8);
    }
  };

  auto mfma_step = [&](int s) {
    ushort* As = smem + s * 16384;
    ushort* Bs = As + 8192;
#pragma unroll
    for (int kh = 0; kh < 2; ++kh) {
      bf16x8 af[4], bf[4];
#pragma unroll
      for (int i = 0; i < 4; ++i) {
        const int row = wm + i * 16 + m16;
        const int slot = (kh * 4 + quad) ^ (row & 7);
        af[i] = *(bf16x8*)&As[row * 64 + slot * 8];
      }
#pragma unroll
      for (int j = 0; j < 4; ++j) {
        const int col = wn + j * 16 + m16;
        const int slot = (kh * 4 + quad) ^ (col & 7);
        bf[j] = *(bf16x8*)&Bs[col * 64 + slot * 8];
      }
#pragma unroll
      for (int i = 0; i < 4; ++i)
#pragma unroll
        for (int j = 0; j < 4; ++j)
          acc[i][j] =
              __builtin_amdgcn_mfma_f32_16x16x32_bf16(af[i], bf[j], acc[i][j], 0, 0, 0);
    }
  };

  load_step(0);
  __syncthreads();
  if (NSTEP > 1) load_step(1);  // DMAs overlap mfma_step(0)
  mfma_step(0);
  if (NSTEP > 1) {
    __syncthreads();  // drains step-1 loads (had mfma(0) time to land)
    mfma_step(1);
  }

  // ---- epilogue: acc -> bf16 -> LDS (pitch 136) -> coalesced 16B stores ----
  __syncthreads();  // all LDS reads done; safe to alias with Ct
  ushort* Ct = smem;
#pragma unroll
  for (int i = 0; i < 4; ++i) {
#pragma unroll
    for (int r = 0; r < 4; ++r) {
      const int row = wm + i * 16 + quad * 4 + r;
#pragma unroll
      for (int j = 0; j < 4; ++j) {
        __hip_bfloat16 h = __float2bfloat16(acc[i][j][r]);
        Ct[row * 136 + wn + j * 16 + m16] = *(ushort*)&h;
      }
    }
  }
  __syncthreads();
  const bool is_xl = (col0 < 256);
  ushort* dst = is_xl ? xlb : xrb;
  const int cb = is_xl ? col0 : (col0 - 256);
  const int chunk = tid & 15;  // 16B chunk within the 256B row
#pragma unroll
  for (int it = 0; it < 8; ++it) {
    const int row = (tid >> 4) + 16 * it;
    const int grow = row0 + row;
    int4 v = *(int4*)&Ct[row * 136 + chunk * 8];
    if (grow < n_nodes)
      *(int4*)(dst + (size_t)grow * 256 + cb + chunk * 8) = v;
  }
}

// ================= CSR build (edges bucketed by dst) =======================
__global__ void k_scan_local(const int* __restrict__ deg, int* __restrict__ rowstart,
                             int* __restrict__ partial, int n) {
  __shared__ int a[256], b[256];
  const int t = threadIdx.x;
  const int i = blockIdx.x * 256 + t;
  const int v = (i < n) ? deg[i] : 0;
  a[t] = v;
  __syncthreads();
  int* cur = a;
  int* nxt = b;
  for (int off = 1; off < 256; off <<= 1) {
    int x = cur[t];
    if (t >= off) x += cur[t - off];
    nxt[t] = x;
    __syncthreads();
    int* tmp = cur; cur = nxt; nxt = tmp;
  }
  const int incl = cur[t];
  if (i < n) rowstart[i] = incl - v;
  if (t == 255) partial[blockIdx.x] = incl;
}

// single-block scan of block sums + zero-fill the 8-entry CSR pad
__global__ void k_scan_partial(int* __restrict__ partial, int nblk,
                               float4* __restrict__ sea, int E_) {
  __shared__ int a[256], b[256];
  const int t = threadIdx.x;
  if (t < 8) sea[E_ + t] = make_float4(0.f, 0.f, 0.f, 0.f);
  const int v = (t < nblk) ? partial[t] : 0;
  a[t] = v;
  __syncthreads();
  int* cur = a;
  int* nxt = b;
  for (int off = 1; off < 256; off <<= 1) {
    int x = cur[t];
    if (t >= off) x += cur[t - off];
    nxt[t] = x;
    __syncthreads();
    int* tmp = cur; cur = nxt; nxt = tmp;
  }
  if (t < nblk) partial[t] = cur[t] - v;
}

__global__ void k_add_off(int* __restrict__ rowstart, int* __restrict__ cursor,
                          const int* __restrict__ partial, int n, int E_) {
  int i = blockIdx.x * blockDim.x + threadIdx.x;
  if (i < n) {
    int v = rowstart[i] + partial[i >> 8];
    rowstart[i] = v;
    cursor[i] = v;
  }
  if (i == 0) rowstart[n] = E_;
}

// ==== fused: cast x -> bf16 A AND CSR edge scatter (src packed in sea.w) ===
__global__ void k_prep(const float* __restrict__ x, ushort* __restrict__ A,
                       const int* __restrict__ ei, const float* __restrict__ ea,
                       int* __restrict__ cursor, float4* __restrict__ sea,
                       int n, int E_) {
  const int nx8 = n * 16;  // 8 elements per thread
  int idx = blockIdx.x * blockDim.x + threadIdx.x;
  if (idx < nx8) {
    const float4* xp = (const float4*)x + (size_t)idx * 2;
    float4 v0 = xp[0], v1 = xp[1];
    float vv[8] = {v0.x, v0.y, v0.z, v0.w, v1.x, v1.y, v1.z, v1.w};
    __align__(16) ushort hb[8];
#pragma unroll
    for (int j = 0; j < 8; ++j) {
      __hip_bfloat16 h = __float2bfloat16(vv[j]);
      hb[j] = *(ushort*)&h;
    }
    *(int4*)(A + (size_t)idx * 8) = *(int4*)hb;
  } else {
    int e = idx - nx8;
    if (e < E_) {
      int dst = ei[E_ + e];
      int pos = atomicAdd(&cursor[dst], 1);
      sea[pos] = make_float4(ea[e * 3], ea[e * 3 + 1], ea[e * 3 + 2],
                             __int_as_float(ei[e]));
    }
  }
}

// ================= fused per-destination attention =========================
// ONE wave per workgroup; chunk dsts per wave; 4-edge software pipeline; src
// index packed in sea.w. MODE 0: bf16 h out. MODE 1: fp32 + PReLU.
__device__ __forceinline__ f32x2 vmax2(f32x2 a, f32x2 b) {
  return (f32x2){fmaxf(a.x, b.x), fmaxf(a.y, b.y)};
}
__device__ __forceinline__ f32x2 vmin2(f32x2 a, f32x2 b) {
  return (f32x2){fminf(a.x, b.x), fminf(a.y, b.y)};
}

__device__ __forceinline__ void edge_step(
    const ushort4& lu, const float4& eav, const f32x2* we0, const f32x2* we1,
    const f32x2* we2, const f32x2* at, const f32x2* xrl, f32x2& num01,
    f32x2& num23, float& den) {
  f32x2 lav0, lav1;
  lav0.x = __uint_as_float((unsigned)lu.x << 16);
  lav0.y = __uint_as_float((unsigned)lu.y << 16);
  lav1.x = __uint_as_float((unsigned)lu.z << 16);
  lav1.y = __uint_as_float((unsigned)lu.w << 16);
  const f32x2 zero = {0.f, 0.f};
  const f32x2 slope = {0.2f, 0.2f};
  f32x2 pv = zero;
#pragma unroll
  for (int j = 0; j < 2; ++j) {
    f32x2 la = (j == 0) ? lav0 : lav1;
    f32x2 ev = we0[j] * eav.x + we1[j] * eav.y + we2[j] * eav.z;
    f32x2 s = la + xrl[j] + ev;
    f32x2 z = vmax2(s, zero) + slope * vmin2(s, zero);
    pv = pv + z * at[j];
  }
  float p = pv.x + pv.y;
  p += __shfl_xor(p, 1);
  p += __shfl_xor(p, 2);
  p += __shfl_xor(p, 4);
  p += __shfl_xor(p, 8);
  const float w = __expf(p);  // |logit| << 80: no max-subtraction needed
  den += w;
  num01 = num01 + (f32x2){w, w} * lav0;
  num23 = num23 + (f32x2){w, w} * lav1;
}

template <int MODE>
__global__ __launch_bounds__(64) void fused_attn(
    const ushort* __restrict__ xlb, const ushort* __restrict__ xrb,
    const int* __restrict__ rowstart, const float4* __restrict__ sea,
    const float* __restrict__ We, const float* __restrict__ att,
    const float* __restrict__ bias, const float* __restrict__ pw,
    float* __restrict__ out, ushort* __restrict__ outs, int n, int chunk) {
  const int lane = threadIdx.x;
  const int d0 = blockIdx.x * chunk;
  if (d0 >= n) return;
  const int d1 = min(d0 + chunk, n);

  // ---- prologue (amortized over the chunk) ----
  f32x2 we0[2], we1[2], we2[2], at[2];
#pragma unroll
  for (int j = 0; j < 4; ++j) {
    int r = 4 * lane + j;
    ((float*)we0)[j] = We[r * 3 + 0];
    ((float*)we1)[j] = We[r * 3 + 1];
    ((float*)we2)[j] = We[r * 3 + 2];
    ((float*)at)[j] = att[r];
  }
  const float4 bias4 = ((const float4*)bias)[lane & 15];
  float4 pw4 = {0.f, 0.f, 0.f, 0.f};
  if (MODE == 1) pw4 = ((const float4*)pw)[lane & 15];
  const ushort4* xlb4 = (const ushort4*)xlb;

  for (int d = d0; d < d1; ++d) {
    const ushort4 xu = ((const ushort4*)xrb)[(unsigned)(d * 64) + lane];
    f32x2 xrl[2];
    xrl[0].x = __uint_as_float((unsigned)xu.x << 16);
    xrl[0].y = __uint_as_float((unsigned)xu.y << 16);
    xrl[1].x = __uint_as_float((unsigned)xu.z << 16);
    xrl[1].y = __uint_as_float((unsigned)xu.w << 16);

    int pos = rowstart[d];
    const int end = rowstart[d + 1];
    f32x2 num01 = {0.f, 0.f}, num23 = {0.f, 0.f};
    float den = 0.f;

    if (pos < end) {
      // CSR padded by 8 zero entries past E: over-read safe; pad/next-dst
      // entries are fetched but never processed. src index rides in sea.w.
      float4 e0 = sea[pos], e1 = sea[pos + 1], e2 = sea[pos + 2], e3 = sea[pos + 3];
      ushort4 g0 = xlb4[(unsigned)(__float_as_int(e0.w) * 64) + lane];
      ushort4 g1 = xlb4[(unsigned)(__float_as_int(e1.w) * 64) + lane];
      ushort4 g2 = xlb4[(unsigned)(__float_as_int(e2.w) * 64) + lane];
      ushort4 g3 = xlb4[(unsigned)(__float_as_int(e3.w) * 64) + lane];

      while (pos + 4 <= end) {
        ushort4 h0 = g0, h1 = g1, h2 = g2, h3 = g3;
        float4 f0 = e0, f1 = e1, f2 = e2, f3 = e3;
        if (pos + 4 < end) {  // uniform branch: prefetch only if more edges
          f0 = sea[pos + 4];
          f1 = sea[pos + 5];
          f2 = sea[pos + 6];
          f3 = sea[pos + 7];
          h0 = xlb4[(unsigned)(__float_as_int(f0.w) * 64) + lane];
          h1 = xlb4[(unsigned)(__float_as_int(f1.w) * 64) + lane];
          h2 = xlb4[(unsigned)(__float_as_int(f2.w) * 64) + lane];
          h3 = xlb4[(unsigned)(__float_as_int(f3.w) * 64) + lane];
        }
        edge_step(g0, e0, we0, we1, we2, at, xrl, num01, num23, den);
        edge_step(g1, e1, we0, we1, we2, at, xrl, num01, num23, den);
        edge_step(g2, e2, we0, we1, we2, at, xrl, num01, num23, den);
        edge_step(g3, e3, we0, we1, we2, at, xrl, num01, num23, den);
        g0 = h0; g1 = h1; g2 = h2; g3 = h3;
        e0 = f0; e1 = f1; e2 = f2; e3 = f3;
        pos += 4;
      }
      const int rem = end - pos;  // 0..3, wave-uniform
      if (rem > 0) edge_step(g0, e0, we0, we1, we2, at, xrl, num01, num23, den);
      if (rem > 1) edge_step(g1, e1, we0, we1, we2, at, xrl, num01, num23, den);
      if (rem > 2) edge_step(g2, e2, we0, we1, we2, at, xrl, num01, num23, den);
    }

    const float inv = 1.f / (den + 1e-16f);
    float4 r;
    r.x = num01.x * inv;
    r.y = num01.y * inv;
    r.z = num23.x * inv;
    r.w = num23.y * inv;
    // combine 4 heads: lanes {m, m+16, m+32, m+48} hold the same channels
    r.x += __shfl_xor(r.x, 16);
    r.y += __shfl_xor(r.y, 16);
    r.z += __shfl_xor(r.z, 16);
    r.w += __shfl_xor(r.w, 16);
    r.x += __shfl_xor(r.x, 32);
    r.y += __shfl_xor(r.y, 32);
    r.z += __shfl_xor(r.z, 32);
    r.w += __shfl_xor(r.w, 32);
    if (lane < 16) {
      float o[4];
      o[0] = 0.25f * r.x + bias4.x;
      o[1] = 0.25f * r.y + bias4.y;
      o[2] = 0.25f * r.z + bias4.z;
      o[3] = 0.25f * r.w + bias4.w;
      if (MODE == 1) {
        const float pwv[4] = {pw4.x, pw4.y, pw4.z, pw4.w};
#pragma unroll
        for (int j = 0; j < 4; ++j) o[j] = (o[j] >= 0.f) ? o[j] : pwv[j] * o[j];
        ((float4*)out)[(size_t)d * 16 + lane] = make_float4(o[0], o[1], o[2], o[3]);
      } else {
        ushort hb[4];
#pragma unroll
        for (int j = 0; j < 4; ++j) {
          __hip_bfloat16 h = __float2bfloat16(o[j]);
          hb[j] = *(ushort*)&h;
        }
        *(ushort4*)(outs + (size_t)d * 64 + 4 * lane) =
            make_ushort4(hb[0], hb[1], hb[2], hb[3]);
      }
    }
  }
}

extern "C" void kernel_launch(void* const* d_in, const int* in_sizes, int n_in,
                              void* d_out, int out_size, void* d_ws, size_t ws_size,
                              hipStream_t stream) {
  const float* x    = (const float*)d_in[0];
  const int*   ei   = (const int*)d_in[1];
  const float* ea   = (const float*)d_in[2];
  const float* Wl1  = (const float*)d_in[3];
  const float* Wr1  = (const float*)d_in[4];
  const float* We1  = (const float*)d_in[5];
  const float* att1 = (const float*)d_in[6];
  const float* b1   = (const float*)d_in[7];
  const float* Wl2  = (const float*)d_in[8];
  const float* Wr2  = (const float*)d_in[9];
  const float* We2  = (const float*)d_in[10];
  const float* att2 = (const float*)d_in[11];
  const float* b2   = (const float*)d_in[12];
  const float* pw   = (const float*)d_in[13];
  const int N_ = in_sizes[0] / 128;
  const int E_ = in_sizes[1] / 2;
  float* out = (float*)d_out;

  char* w = (char*)d_ws;
  auto alloc = [&](size_t bytes) {
    char* p = w;
    w += (bytes + 255) & ~size_t(255);
    return p;
  };
  ushort* xlb      = (ushort*)alloc((size_t)N_ * 256 * 2);   // bf16 gather operand
  ushort* xrb      = (ushort*)alloc((size_t)N_ * 256 * 2);   // bf16 logit operand
  ushort* Ax       = (ushort*)alloc((size_t)N_ * 128 * 2);   // bf16 cast of x
  ushort* h2       = (ushort*)alloc((size_t)N_ * 64 * 2);    // bf16 h (layer-2 A)
  float4* sea      = (float4*)alloc((size_t)(E_ + 8) * 16);  // {ea0,ea1,ea2,src}
  int*    deg      = (int*)alloc((size_t)N_ * 4);
  int*    rowstart = (int*)alloc((size_t)(N_ + 1) * 4);
  int*    cursor   = (int*)alloc((size_t)N_ * 4);
  int*    partial  = (int*)alloc(256 * 4);
  ushort* WT1      = (ushort*)alloc((size_t)512 * 128 * 2);
  ushort* WT2      = (ushort*)alloc((size_t)512 * 64 * 2);

  // ---- weight casts + histogram (deg zeroed via async memset) ----
  hipMemsetAsync(deg, 0, (size_t)N_ * 4, stream);
  const int wtot = 512 * 128 + 512 * 64 + E_;
  k_weights_hist<<<(wtot + 255) / 256, 256, 0, stream>>>(Wl1, Wr1, WT1, Wl2, Wr2, WT2,
                                                         ei, deg, E_);

  // ---- CSR build (parallel 3-kernel scan) + x cast + edge scatter ----
  const int nblk = (N_ + 255) / 256;
  k_scan_local<<<nblk, 256, 0, stream>>>(deg, rowstart, partial, N_);
  k_scan_partial<<<1, 256, 0, stream>>>(partial, nblk, sea, E_);
  k_add_off<<<nblk, 256, 0, stream>>>(rowstart, cursor, partial, N_, E_);
  const int ptot = N_ * 16 + E_;
  k_prep<<<(ptot + 255) / 256, 256, 0, stream>>>(x, Ax, ei, ea, cursor, sea, N_, E_);

  const dim3 GG(4, (N_ + 127) / 128);  // x: col-blocks (xl,xl,xr,xr); y: rows
  const int chunk = 2;                 // dsts per wave
  const int FB = (N_ + chunk - 1) / chunk;  // one wave per block

  // ---- layer 1 ----
  gemm_mfma<128><<<GG, 256, 0, stream>>>(Ax, WT1, xlb, xrb, N_);
  fused_attn<0><<<FB, 64, 0, stream>>>(xlb, xrb, rowstart, sea, We1, att1,
                                       b1, pw, nullptr, h2, N_, chunk);
  // ---- layer 2 ----
  gemm_mfma<64><<<GG, 256, 0, stream>>>(h2, WT2, xlb, xrb, N_);
  fused_attn<1><<<FB, 64, 0, stream>>>(xlb, xrb, rowstart, sea, We2, att2,
                                       b2, pw, out, nullptr, N_, chunk);
}